// Round 10
// baseline (292.557 us; speedup 1.0000x reference)
//
#include <hip/hip_runtime.h>
#include <hip/hip_bf16.h>
#include <math.h>

#define T_DIM 1024
#define B_DIM 8
#define D_DIM 1024
#define H_DIM 16
#define DH 64
#define M_ROWS 8192          // T*B
#define N_COLS 5120          // 5*D
#define K_DIM 1024
#define PAD 72               // padded bf16 row length (144 B): b128-aligned, conflict-free

typedef __attribute__((ext_vector_type(8))) short short8;
typedef __attribute__((ext_vector_type(4))) float floatx4;

static __device__ __forceinline__ unsigned short f2bf(float f){
    unsigned int u = __float_as_uint(f);
    u += 0x7fff + ((u >> 16) & 1);          // RNE
    return (unsigned short)(u >> 16);
}
static __device__ __forceinline__ float sigf(float x){
    return 1.f / (1.f + __expf(-x));
}

// DPP butterfly adds on VALU pipe
#define DPPADD(x, ctrl) ((x) + __int_as_float(__builtin_amdgcn_update_dpp(0, __float_as_int(x), (ctrl), 0xF, 0xF, true)))
static __device__ __forceinline__ float red16(float x){
    x = DPPADD(x, 0xB1); x = DPPADD(x, 0x4E); x = DPPADD(x, 0x141); x = DPPADD(x, 0x140); return x;
}

// ---------------- fp32 -> bf16 conversion ----------------
__global__ void cvt_bf16(const float* __restrict__ src, unsigned short* __restrict__ dst, int n4){
    int i = blockIdx.x*blockDim.x + threadIdx.x;
    int stride = gridDim.x*blockDim.x;
    for (; i < n4; i += stride){
        float4 f = ((const float4*)src)[i];
        ushort4 o;
        o.x = f2bf(f.x); o.y = f2bf(f.y); o.z = f2bf(f.z); o.w = f2bf(f.w);
        ((ushort4*)dst)[i] = o;
    }
}

__global__ void cvt_w(const float* __restrict__ w0, const float* __restrict__ w1,
                      const float* __restrict__ w2, const float* __restrict__ w3,
                      const float* __restrict__ w4, unsigned short* __restrict__ dst){
    int i = blockIdx.x*blockDim.x + threadIdx.x;
    int seg = i >> 18;
    int off = i & 262143;
    const float* src = (seg==0)?w0:(seg==1)?w1:(seg==2)?w2:(seg==3)?w3:w4;
    float4 f = ((const float4*)src)[off];
    ushort4 o;
    o.x = f2bf(f.x); o.y = f2bf(f.y); o.z = f2bf(f.z); o.w = f2bf(f.w);
    ((ushort4*)dst)[i] = o;
}

// ---------------- NT GEMM + fused epilogue (256^2, 8 waves, ring-4) ----------------
// KQV record per (bh,t): 512 B = [khat bf16 x64 | qhat bf16 x64 | v fp32 x64]
// gates -> G[bh][t] = {alpha, beta} fp32
#define GLD16(g, l) __builtin_amdgcn_global_load_lds(                         \
    (const __attribute__((address_space(1))) void*)(g),                       \
    (__attribute__((address_space(3))) void*)(l), 16, 0, 0)

#define SBAR() do { asm volatile("" ::: "memory"); __builtin_amdgcn_s_barrier(); asm volatile("" ::: "memory"); } while(0)

// stage one k-slice (256 rows x 32 k for A and B) into ring slot (512 threads -> 4 GLD16)
#define STAGE(slot, kk) do {                                                  \
    GLD16(pA0 + (kk)*32, &As[slot][tid*8]);                                   \
    GLD16(pA1 + (kk)*32, &As[slot][4096 + tid*8]);                            \
    GLD16(pB0 + (kk)*32, &Bs[slot][tid*8]);                                   \
    GLD16(pB1 + (kk)*32, &Bs[slot][4096 + tid*8]); } while(0)

#define READ_FRAGS(aF, bF, slot) do {                                         \
    aF[0] = *(const short8*)&As[slot][rowA];                                  \
    _Pragma("unroll")                                                         \
    for (int n = 0; n < 4; ++n) bF[n] = *(const short8*)&Bs[slot][rowB + n*512]; \
    _Pragma("unroll")                                                         \
    for (int m = 1; m < 8; ++m) aF[m] = *(const short8*)&As[slot][rowA + m*512]; \
} while(0)

#define MFMA_ALL(aF, bF) do {                                                 \
    __builtin_amdgcn_s_setprio(1);                                            \
    _Pragma("unroll")                                                         \
    for (int m = 0; m < 8; ++m)                                               \
        _Pragma("unroll")                                                     \
        for (int n = 0; n < 4; ++n)                                           \
            acc[m][n] = __builtin_amdgcn_mfma_f32_16x16x32_bf16(aF[m], bF[n], acc[m][n], 0,0,0); \
    __builtin_amdgcn_s_setprio(0);                                            \
} while(0)

__global__ __launch_bounds__(512, 2) void gemm_bt(const unsigned short* __restrict__ A,
                                                  const unsigned short* __restrict__ B,
                                                  unsigned char* __restrict__ KQV,
                                                  float* __restrict__ G,
                                                  const float* __restrict__ b_alpha,
                                                  const float* __restrict__ b_beta){
    // ring of 4 k-slices per operand, 16 KiB each (256 rows x 32 k bf16), XOR-swizzled
    __shared__ unsigned short As[4][8192];
    __shared__ unsigned short Bs[4][8192];
    const int tid = threadIdx.x;

    // XCD-aware bijective swizzle over 640 blocks; within-XCD chunks of 4 rows x 5 cols
    const int bid = blockIdx.y * 20 + blockIdx.x;
    const int xcd = bid & 7, idx = bid >> 3;          // idx in 0..79
    const int ch = idx / 20, w20 = idx % 20;
    const int rowBase = (xcd*4 + (w20 & 3)) * 256;
    const int colBase = (ch*5 + (w20 >> 2)) * 256;

    const int l = tid & 63, l15 = l & 15, quad = l >> 4;
    const int wv = tid >> 6, wr = wv >> 2, wc = wv & 3;   // 2 M-waves x 4 N-waves

    // read-side swizzle: logical k-group quad lives at kg = quad ^ ((row>>1)&3)
    const int fk   = (quad ^ ((l15 >> 1) & 3)) * 8;
    const int rowA = (wr*128 + l15)*32 + fk;              // + m*512 within slice
    const int rowB = (wc*64  + l15)*32 + fk;              // + n*512 within slice

    // stage-side inverse swizzle baked into the GLOBAL source column
    const int kOff = ((tid & 3) ^ ((tid >> 3) & 3)) * 8;
    const unsigned short* pA0 = A + (size_t)(rowBase + (tid >> 2)) * K_DIM + kOff;
    const unsigned short* pA1 = pA0 + (size_t)128 * K_DIM;
    const unsigned short* pB0 = B + (size_t)(colBase + (tid >> 2)) * K_DIM + kOff;
    const unsigned short* pB1 = pB0 + (size_t)128 * K_DIM;

    floatx4 acc[8][4] = {};
    short8 aF0[8], bF0[4], aF1[8], bF1[4];

    // prologue: slices 0,1,2 staged; slice 0 frags pre-read into buf0; slice 1 published.
    STAGE(0, 0); STAGE(1, 1); STAGE(2, 2);
    asm volatile("s_waitcnt vmcnt(8)" ::: "memory");   // slice 0 landed
    SBAR();
    READ_FRAGS(aF0, bF0, 0);
    asm volatile("s_waitcnt vmcnt(4)" ::: "memory");   // slice 1 landed
    SBAR();

    // 32 phases. Phase kk: issue ds_reads of slice kk+1 (just published) into the
    // spare reg buffer, issue STAGE(kk+3), then MFMA slice kk from the other buffer.
    for (int kk = 0; kk < 32; kk += 2){
        // even phase: MFMA buf0, read into buf1
        READ_FRAGS(aF1, bF1, (kk+1)&3);
        if (kk < 29) STAGE((kk+3)&3, kk+3);
        MFMA_ALL(aF0, bF0);
        if (kk < 29) asm volatile("s_waitcnt vmcnt(4)" ::: "memory");
        SBAR();
        // odd phase: MFMA buf1, read into buf0
        if (kk+1 < 31) READ_FRAGS(aF0, bF0, (kk+2)&3);
        if (kk+1 < 29) STAGE((kk+4)&3, kk+4);
        MFMA_ALL(aF1, bF1);
        if (kk+1 < 29)       asm volatile("s_waitcnt vmcnt(4)" ::: "memory");
        else if (kk+1 == 29) asm volatile("s_waitcnt vmcnt(0)" ::: "memory");
        SBAR();
    }

    // ---------------- fused epilogue ----------------
    const int gcol = colBase + wc*64;        // wave covers exactly one head (64 cols)
    const int seg  = gcol >> 10;             // 0=q, 1=k, 2=v, 3=alpha, 4=beta
    const int rbw  = rowBase + wr*128 + quad*4;
    if (seg < 2){
        const int h = (gcol >> 6) & 15;
        const int segOff = (seg == 0) ? 128 : 0;
        #pragma unroll
        for (int m = 0; m < 8; ++m){
            #pragma unroll
            for (int r = 0; r < 4; ++r){
                float ss = acc[m][0][r]*acc[m][0][r] + acc[m][1][r]*acc[m][1][r]
                         + acc[m][2][r]*acc[m][2][r] + acc[m][3][r]*acc[m][3][r];
                ss = red16(ss);
                const float rn = 1.f / fmaxf(sqrtf(ss), 1e-12f);
                const int row = rbw + m*16 + r;
                const size_t rec = (size_t)((row & 7)*16 + h)*1024 + (row >> 3);
                unsigned short* rp = (unsigned short*)(KQV + rec*512 + segOff);
                #pragma unroll
                for (int n = 0; n < 4; ++n)
                    rp[n*16 + l15] = f2bf(acc[m][n][r] * rn);
            }
        }
    } else if (seg == 2){
        const int h = (gcol >> 6) & 15;
        #pragma unroll
        for (int m = 0; m < 8; ++m){
            #pragma unroll
            for (int r = 0; r < 4; ++r){
                const int row = rbw + m*16 + r;
                const size_t rec = (size_t)((row & 7)*16 + h)*1024 + (row >> 3);
                float* vp = (float*)(KQV + rec*512 + 256);
                #pragma unroll
                for (int n = 0; n < 4; ++n)
                    vp[n*16 + l15] = acc[m][n][r];
            }
        }
    } else {
        const int isBeta = (seg == 4) ? 1 : 0;
        const float* bias = isBeta ? b_beta : b_alpha;
        const int gcol0 = gcol - (isBeta ? 4096 : 3072);
        const int hh = gcol0 >> 6;
        float bj[4];
        #pragma unroll
        for (int n = 0; n < 4; ++n) bj[n] = bias[gcol0 + n*16 + l15];
        #pragma unroll
        for (int m = 0; m < 8; ++m){
            #pragma unroll
            for (int r = 0; r < 4; ++r){
                float sum = 0.f;
                #pragma unroll
                for (int n = 0; n < 4; ++n) sum += sigf(acc[m][n][r] + bj[n]);
                sum = red16(sum);
                if (l15 == 0){
                    const int row = rbw + m*16 + r;
                    const int tt = row >> 3, bb = row & 7;
                    G[(((size_t)(bb*16 + hh)*1024 + tt))*2 + isBeta] = sum * (1.f/64.f);
                }
            }
        }
    }
}

// ---------------- Phase A: per-(bh,chunk) coefficients ----------------
// Forward substitution is BLOCKED 16x16: only a 16-float register array is
// live at a time (guaranteed full unroll -> no scratch spill, rule #20);
// cross-block contributions go through the sX LDS mirror (conflict-free).
__global__ __launch_bounds__(256) void phasea(const unsigned char* __restrict__ KQV,
                                              const float* __restrict__ G,
                                              unsigned short* __restrict__ Wtg,
                                              unsigned short* __restrict__ Ng,
                                              float* __restrict__ rg){
    __shared__ unsigned short sKa[64*PAD], sQa[64*PAD];
    __shared__ float sAB[128];
    __shared__ float sKK[4096];
    __shared__ float sX[4096];
    __shared__ float sR[64], sRi[64];

    const int unitIdx = blockIdx.x;
    const int bh = unitIdx >> 4, c = unitIdx & 15;
    const int tid = threadIdx.x;
    const int w = tid>>6, l = tid&63, l15 = l&15, quad = l>>4;
    const unsigned char* gRec = KQV + ((size_t)bh*1024 + c*64)*512;

    #pragma unroll
    for (int it=0; it<2; ++it){
        int flat = it*256 + tid, t = flat>>3, i8 = flat&7;
        float4 kv = *(const float4*)(gRec + t*512 + i8*16);
        float4 qv = *(const float4*)(gRec + t*512 + 128 + i8*16);
        *(float4*)&sKa[t*PAD + i8*8] = kv;
        *(float4*)&sQa[t*PAD + i8*8] = qv;
    }
    if (tid < 64){
        float2 ab = *(const float2*)(G + ((size_t)bh*1024 + c*64 + tid)*2);
        sAB[tid*2] = ab.x; sAB[tid*2+1] = ab.y;
    }
    __syncthreads();
    if (tid < 64){
        float p = sAB[tid*2];
        #pragma unroll
        for (int off=1; off<64; off<<=1){
            float y = __shfl_up(p, off);
            if (tid >= off) p *= y;
        }
        sR[tid] = p; sRi[tid] = 1.f/p;
    }
    __syncthreads();

    // KK (waves 0,1) / QK->N (waves 2,3)
    {
        const int isQK = w >> 1;
        const int tmb = (w & 1)*2;
        floatx4 acc[2][4] = {};
        #pragma unroll
        for (int ks=0; ks<2; ++ks){
            short8 aA[2]; short8 bB[4];
            #pragma unroll
            for (int i=0;i<2;++i)
                aA[i] = *(const short8*)&((isQK? sQa : sKa)[((tmb+i)*16 + l15)*PAD + ks*32 + quad*8]);
            #pragma unroll
            for (int j2=0;j2<4;++j2)
                bB[j2] = *(const short8*)&sKa[(j2*16 + l15)*PAD + ks*32 + quad*8];
            #pragma unroll
            for (int i=0;i<2;++i)
                #pragma unroll
                for (int j2=0;j2<4;++j2)
                    acc[i][j2] = __builtin_amdgcn_mfma_f32_16x16x32_bf16(aA[i], bB[j2], acc[i][j2], 0,0,0);
        }
        #pragma unroll
        for (int i=0;i<2;++i){
            #pragma unroll
            for (int j2=0;j2<4;++j2){
                #pragma unroll
                for (int r=0;r<4;++r){
                    int t = (tmb+i)*16 + quad*4 + r;
                    int s = j2*16 + l15;
                    float ratio = sR[t]*sRi[s];
                    if (!isQK){
                        sKK[t*64+s] = (s < t) ? sAB[t*2+1]*ratio*acc[i][j2][r] : 0.f;
                    } else {
                        float nv = (s <= t) ? ratio*acc[i][j2][r] : 0.f;
                        Ng[(size_t)unitIdx*4096 + t*64 + s] = f2bf(nv);
                    }
                }
            }
        }
    }
    __syncthreads();

    // X = (I+C)^-1, column-parallel blocked forward substitution on wave 0.
    // Lane s owns column s. Per 16-row block: chain-free "off" part reads
    // prior blocks from sX (lane-consecutive, conflict-free; sKK reads are
    // wave-uniform broadcasts), then a 16-step serial recurrence on a
    // 16-float register array (fully unrolled, static indices).
    if (tid < 64){
        const int s = tid;
        const float be = sAB[s*2+1];
        #pragma unroll
        for (int ib = 0; ib < 4; ++ib){
            const int tb = ib*16;
            float off[16];
            #pragma unroll
            for (int tt = 0; tt < 16; ++tt) off[tt] = 0.f;
            for (int r = 0; r < tb; ++r){            // tb is constant per unrolled ib
                float xr = sX[r*64 + s];
                #pragma unroll
                for (int tt = 0; tt < 16; ++tt)
                    off[tt] += sKK[(tb+tt)*64 + r] * xr;
            }
            float X16[16];
            #pragma unroll
            for (int tt = 0; tt < 16; ++tt){
                const int t = tb + tt;
                float a = off[tt];
                #pragma unroll
                for (int rr = 0; rr < 16; ++rr){
                    if (rr < tt) a += sKK[t*64 + tb + rr] * X16[rr];
                }
                X16[tt] = (s == t) ? 1.f : -a;
            }
            #pragma unroll
            for (int tt = 0; tt < 16; ++tt){
                sX[(tb+tt)*64 + s] = X16[tt];
                Wtg[(size_t)unitIdx*4096 + (size_t)(tb+tt)*64 + s] = f2bf(X16[tt]*be);
            }
        }
        rg[(size_t)unitIdx*64 + s] = sR[s];
    }
}

// ---------------- Phase B: sequential chunk scan via MFMA ----------------
// 256 blocks = (half*128 + bh); 512 threads = 8 waves: wt = w&3 (t-tile),
// wg = w>>2 (d-quarter). 3 barriers/chunk: scaled-K build moved to stage 1
// (own buffer sKt2 removes the sKtU overwrite hazard that forced barrier B').
__global__ __launch_bounds__(512) void chunk_scan(const unsigned char* __restrict__ KQV,
                                                  const unsigned short* __restrict__ Wtg,
                                                  const unsigned short* __restrict__ Ng,
                                                  const float* __restrict__ rg,
                                                  const float* __restrict__ S0g,
                                                  float* __restrict__ out){
    __shared__ unsigned short sK[64*PAD], sQ[64*PAD], sWt[64*PAD];
    __shared__ unsigned short sN[2][64*PAD];
    __shared__ unsigned short sUt[32*PAD];
    __shared__ unsigned short sKtU[32*PAD];   // RHS^T (d2-local rows 0..31)
    __shared__ unsigned short sKt2[64*PAD];   // scaled K~^T (d_k rows 0..63)
    __shared__ unsigned short sS0b[32*PAD];
    __shared__ float sr[2][64];

    const int bh = blockIdx.x & 127;
    const int half = blockIdx.x >> 7;
    const int b = bh >> 4, h = bh & 15;
    const int tid = threadIdx.x;
    const int w = tid >> 6, l = tid & 63, l15 = l & 15, quad = l >> 4;
    const int wt = w & 3, wg = w >> 2;
    const int t0 = wt*16 + quad*4;
    const int dq = wg*16;
    const int d2base = dq + quad*4;
    const unsigned char* gRec = KQV + (size_t)bh * (1024*512);
    const size_t outBase = (size_t)b*1024 + h*64 + half*32;

    float4 kst, qst, wst, nst;
    float rst = 0.f;
    float vCur[4], vNext[4];
    floatx4 Sreg;

    // prologue: chunk 0
    {
        const int unit = bh*16;
        const int t = tid>>3, i8 = tid&7;
        kst = *(const float4*)(gRec + t*512 +       i8*16);
        qst = *(const float4*)(gRec + t*512 + 128 + i8*16);
        wst = *(const float4*)((const unsigned char*)Wtg + (size_t)unit*8192 + (size_t)tid*16);
        nst = *(const float4*)((const unsigned char*)Ng  + (size_t)unit*8192 + (size_t)tid*16);
        if (tid < 64) rst = rg[(size_t)unit*64 + tid];
        #pragma unroll
        for (int r=0; r<4; ++r)
            vCur[r] = *(const float*)(gRec + (t0+r)*512 + 256 + (half*32 + dq + l15)*4);
        #pragma unroll
        for (int r=0;r<4;++r)
            Sreg[r] = S0g[(size_t)bh*4096 + (half*32 + d2base + r)*64 + wt*16 + l15];
        *(float4*)&sK[t*PAD + i8*8]    = kst;
        *(float4*)&sQ[t*PAD + i8*8]    = qst;
        *(float4*)&sWt[t*PAD + i8*8]   = wst;
        *(float4*)&sN[0][t*PAD + i8*8] = nst;
        if (tid < 64) sr[0][tid] = rst;
        #pragma unroll
        for (int r=0;r<4;++r)
            sS0b[(d2base+r)*PAD + wt*16 + l15] = f2bf(Sreg[r]);
    }
    __syncthreads();

    for (int c=0; c<16; ++c){
        const int buf = c & 1;
        if (c < 15){
            const int unit = bh*16 + c + 1;
            const unsigned char* gRecN = gRec + (size_t)(c+1)*64*512;
            const int t = tid>>3, i8 = tid&7;
            kst = *(const float4*)(gRecN + t*512 +       i8*16);
            qst = *(const float4*)(gRecN + t*512 + 128 + i8*16);
            wst = *(const float4*)((const unsigned char*)Wtg + (size_t)unit*8192 + (size_t)tid*16);
            nst = *(const float4*)((const unsigned char*)Ng  + (size_t)unit*8192 + (size_t)tid*16);
            if (tid < 64) rst = rg[(size_t)unit*64 + tid];
            #pragma unroll
            for (int r=0;r<4;++r)
                vNext[r] = *(const float*)(gRecN + (t0+r)*512 + 256 + (half*32 + dq + l15)*4);
        }

        // stage 1: PT = K*S0^T, OB = Q*S0^T; RHS^T write; scaled-K~^T build (indep).
        floatx4 accPT = {}; floatx4 accOB = {};
        #pragma unroll
        for (int ks=0; ks<2; ++ks){
            short8 aK = *(const short8*)&sK[(wt*16 + l15)*PAD + ks*32 + quad*8];
            short8 aQ = *(const short8*)&sQ[(wt*16 + l15)*PAD + ks*32 + quad*8];
            short8 bS = *(const short8*)&sS0b[(dq + l15)*PAD + ks*32 + quad*8];
            accPT = __builtin_amdgcn_mfma_f32_16x16x32_bf16(aK, bS, accPT, 0,0,0);
            accOB = __builtin_amdgcn_mfma_f32_16x16x32_bf16(aQ, bS, accOB, 0,0,0);
        }
        float r4[4];
        #pragma unroll
        for (int r=0;r<4;++r) r4[r] = sr[buf][t0+r];
        {
            float x0 = vCur[0] - r4[0]*accPT[0];
            float x1 = vCur[1] - r4[1]*accPT[1];
            float x2 = vCur[2] - r4[2]*accPT[2];
            float x3 = vCur[3] - r4[3]*accPT[3];
            uint2 uu;
            uu.x = (unsigned)f2bf(x0) | ((unsigned)f2bf(x1)<<16);
            uu.y = (unsigned)f2bf(x2) | ((unsigned)f2bf(x3)<<16);
            *(uint2*)&sKtU[(dq + l15)*PAD + t0] = uu;     // RHS^T[d2][t]
        }
        {   // scaled K~^T: reads sK, sr only (stable since chunk start)
            const float rl = sr[buf][63];
            const int e = tid >> 3, sb = (tid & 7)*8;
            #pragma unroll
            for (int j2=0; j2<8; ++j2){
                int s = sb + j2;
                float kv = __uint_as_float((unsigned)sK[s*PAD + e] << 16);
                sKt2[e*PAD + s] = f2bf(kv * (rl / sr[buf][s]));
            }
        }
        __syncthreads();   // A: RHS^T + K~^T published

        // stage 2: U = Wt * RHS^T; write U^T
        floatx4 accU = {};
        #pragma unroll
        for (int ks=0; ks<2; ++ks){
            short8 aW = *(const short8*)&sWt[(wt*16 + l15)*PAD + ks*32 + quad*8];
            short8 bR = *(const short8*)&sKtU[(dq + l15)*PAD + ks*32 + quad*8];
            accU = __builtin_amdgcn_mfma_f32_16x16x32_bf16(aW, bR, accU, 0,0,0);
        }
        {
            uint2 uu;
            uu.x = (unsigned)f2bf(accU[0]) | ((unsigned)f2bf(accU[1])<<16);
            uu.y = (unsigned)f2bf(accU[2]) | ((unsigned)f2bf(accU[3])<<16);
            *(uint2*)&sUt[(dq + l15)*PAD + t0] = uu;
        }
        __syncthreads();   // B: U^T published

        // stage 3: O = diag(r)*OB + N*U^T ;  S = rl*S0 + U^T * K~^T
        floatx4 accO;
        #pragma unroll
        for (int r=0;r<4;++r) accO[r] = r4[r]*accOB[r];
        #pragma unroll
        for (int ks=0; ks<2; ++ks){
            short8 aN = *(const short8*)&sN[buf][(wt*16 + l15)*PAD + ks*32 + quad*8];
            short8 bU = *(const short8*)&sUt[(dq + l15)*PAD + ks*32 + quad*8];
            accO = __builtin_amdgcn_mfma_f32_16x16x32_bf16(aN, bU, accO, 0,0,0);
        }
        const float rl = sr[buf][63];
        floatx4 accS;
        #pragma unroll
        for (int r=0;r<4;++r) accS[r] = rl*Sreg[r];
        #pragma unroll
        for (int ks=0; ks<2; ++ks){
            short8 aU = *(const short8*)&sUt[(dq + l15)*PAD + ks*32 + quad*8];
            short8 bK = *(const short8*)&sKt2[(wt*16 + l15)*PAD + ks*32 + quad*8];
            accS = __builtin_amdgcn_mfma_f32_16x16x32_bf16(aU, bK, accS, 0,0,0);
        }
        Sreg = accS;

        #pragma unroll
        for (int r=0;r<4;++r)
            out[(size_t)(c*64 + t0 + r)*8192 + outBase + dq + l15] = accO[r];
        #pragma unroll
        for (int r=0;r<4;++r)
            sS0b[(d2base + r)*PAD + wt*16 + l15] = f2bf(Sreg[r]);

        if (c < 15){
            const int t = tid>>3, i8 = tid&7;
            *(float4*)&sK[t*PAD + i8*8]         = kst;
            *(float4*)&sQ[t*PAD + i8*8]         = qst;
            *(float4*)&sWt[t*PAD + i8*8]        = wst;
            *(float4*)&sN[buf^1][t*PAD + i8*8]  = nst;
            if (tid < 64) sr[buf^1][tid] = rst;
            #pragma unroll
            for (int r=0;r<4;++r) vCur[r] = vNext[r];
        }
        __syncthreads();   // C: end of chunk
    }

    // final state
    #pragma unroll
    for (int r=0;r<4;++r)
        out[(size_t)8388608 + (size_t)bh*4096 + (half*32 + d2base + r)*64 + wt*16 + l15] = Sreg[r];
}

extern "C" void kernel_launch(void* const* d_in, const int* in_sizes, int n_in,
                              void* d_out, int out_size, void* d_ws, size_t ws_size,
                              hipStream_t stream){
    const float* x  = (const float*)d_in[0];
    const float* S0 = (const float*)d_in[1];
    const float* Wq = (const float*)d_in[2];
    const float* Wk = (const float*)d_in[3];
    const float* Wv = (const float*)d_in[4];
    const float* Wa = (const float*)d_in[5];
    const float* ba = (const float*)d_in[6];
    const float* Wb = (const float*)d_in[7];
    const float* bb = (const float*)d_in[8];
    float* out = (float*)d_out;

    char* ws = (char*)d_ws;
    unsigned short* Abf = (unsigned short*)ws;                    // 16,777,216
    unsigned short* Bbf = (unsigned short*)(ws + 16777216);       // 10,485,760
    unsigned char*  KQV = (unsigned char*) (ws + 27262976);       // 67,108,864 (128*1024*512)
    float*          G   = (float*)         (ws + 94371840);       //  1,048,576
    unsigned short* Wtg = (unsigned short*)(ws + 95420416);       // 16,777,216 (2048*4096 bf16)
    unsigned short* Ng  = (unsigned short*)(ws + 112197632);      // 16,777,216
    float*          rg  = (float*)         (ws + 128974848);      //    524,288  -> end 129,499,136

    cvt_bf16<<<2048, 256, 0, stream>>>(x, Abf, (M_ROWS*K_DIM)/4);
    cvt_w<<<5120, 256, 0, stream>>>(Wq, Wk, Wv, Wa, Wb, Bbf);

    dim3 gg(N_COLS/256, M_ROWS/256);   // 20 x 32 = 640 blocks, 512 threads
    gemm_bt<<<gg, 512, 0, stream>>>(Abf, Bbf, KQV, G, ba, bb);

    phasea<<<2048, 256, 0, stream>>>(KQV, G, Wtg, Ng, rg);

    chunk_scan<<<256, 512, 0, stream>>>(KQV, Wtg, Ng, rg, S0, out);
}

// Round 11
// 281.812 us; speedup vs baseline: 1.0381x; 1.0381x over previous
//
#include <hip/hip_runtime.h>
#include <hip/hip_bf16.h>
#include <math.h>

#define T_DIM 1024
#define B_DIM 8
#define D_DIM 1024
#define H_DIM 16
#define DH 64
#define M_ROWS 8192          // T*B
#define N_COLS 5120          // 5*D
#define K_DIM 1024
#define PAD 72               // padded bf16 row length (144 B): b128-aligned, conflict-free

typedef __attribute__((ext_vector_type(8))) short short8;
typedef __attribute__((ext_vector_type(4))) float floatx4;

static __device__ __forceinline__ unsigned short f2bf(float f){
    unsigned int u = __float_as_uint(f);
    u += 0x7fff + ((u >> 16) & 1);          // RNE
    return (unsigned short)(u >> 16);
}
static __device__ __forceinline__ float sigf(float x){
    return 1.f / (1.f + __expf(-x));
}

// DPP butterfly adds on VALU pipe
#define DPPADD(x, ctrl) ((x) + __int_as_float(__builtin_amdgcn_update_dpp(0, __float_as_int(x), (ctrl), 0xF, 0xF, true)))
static __device__ __forceinline__ float red16(float x){
    x = DPPADD(x, 0xB1); x = DPPADD(x, 0x4E); x = DPPADD(x, 0x141); x = DPPADD(x, 0x140); return x;
}

// ---------------- fp32 -> bf16 conversion ----------------
__global__ void cvt_bf16(const float* __restrict__ src, unsigned short* __restrict__ dst, int n4){
    int i = blockIdx.x*blockDim.x + threadIdx.x;
    int stride = gridDim.x*blockDim.x;
    for (; i < n4; i += stride){
        float4 f = ((const float4*)src)[i];
        ushort4 o;
        o.x = f2bf(f.x); o.y = f2bf(f.y); o.z = f2bf(f.z); o.w = f2bf(f.w);
        ((ushort4*)dst)[i] = o;
    }
}

__global__ void cvt_w(const float* __restrict__ w0, const float* __restrict__ w1,
                      const float* __restrict__ w2, const float* __restrict__ w3,
                      const float* __restrict__ w4, unsigned short* __restrict__ dst){
    int i = blockIdx.x*blockDim.x + threadIdx.x;
    int seg = i >> 18;
    int off = i & 262143;
    const float* src = (seg==0)?w0:(seg==1)?w1:(seg==2)?w2:(seg==3)?w3:w4;
    float4 f = ((const float4*)src)[off];
    ushort4 o;
    o.x = f2bf(f.x); o.y = f2bf(f.y); o.z = f2bf(f.z); o.w = f2bf(f.w);
    ((ushort4*)dst)[i] = o;
}

// ---------------- NT GEMM + fused epilogue (256^2, 8 waves, ring-4) ----------------
// KQV record per (bh,t): 512 B = [khat bf16 x64 | qhat bf16 x64 | v fp32 x64]
// gates -> G[bh][t] = {alpha, beta} fp32
#define GLD16(g, l) __builtin_amdgcn_global_load_lds(                         \
    (const __attribute__((address_space(1))) void*)(g),                       \
    (__attribute__((address_space(3))) void*)(l), 16, 0, 0)

#define SBAR() do { asm volatile("" ::: "memory"); __builtin_amdgcn_s_barrier(); asm volatile("" ::: "memory"); } while(0)

// stage one k-slice (256 rows x 32 k for A and B) into ring slot (512 threads -> 4 GLD16)
#define STAGE(slot, kk) do {                                                  \
    GLD16(pA0 + (kk)*32, &As[slot][tid*8]);                                   \
    GLD16(pA1 + (kk)*32, &As[slot][4096 + tid*8]);                            \
    GLD16(pB0 + (kk)*32, &Bs[slot][tid*8]);                                   \
    GLD16(pB1 + (kk)*32, &Bs[slot][4096 + tid*8]); } while(0)

#define READ_FRAGS(aF, bF, slot) do {                                         \
    aF[0] = *(const short8*)&As[slot][rowA];                                  \
    _Pragma("unroll")                                                         \
    for (int n = 0; n < 4; ++n) bF[n] = *(const short8*)&Bs[slot][rowB + n*512]; \
    _Pragma("unroll")                                                         \
    for (int m = 1; m < 8; ++m) aF[m] = *(const short8*)&As[slot][rowA + m*512]; \
} while(0)

#define MFMA_ALL(aF, bF) do {                                                 \
    __builtin_amdgcn_s_setprio(1);                                            \
    _Pragma("unroll")                                                         \
    for (int m = 0; m < 8; ++m)                                               \
        _Pragma("unroll")                                                     \
        for (int n = 0; n < 4; ++n)                                           \
            acc[m][n] = __builtin_amdgcn_mfma_f32_16x16x32_bf16(aF[m], bF[n], acc[m][n], 0,0,0); \
    __builtin_amdgcn_s_setprio(0);                                            \
} while(0)

__global__ __launch_bounds__(512, 2) void gemm_bt(const unsigned short* __restrict__ A,
                                                  const unsigned short* __restrict__ B,
                                                  unsigned char* __restrict__ KQV,
                                                  float* __restrict__ G,
                                                  const float* __restrict__ b_alpha,
                                                  const float* __restrict__ b_beta){
    // ring of 4 k-slices per operand, 16 KiB each (256 rows x 32 k bf16), XOR-swizzled
    __shared__ unsigned short As[4][8192];
    __shared__ unsigned short Bs[4][8192];
    const int tid = threadIdx.x;

    // XCD-aware bijective swizzle over 640 blocks; within-XCD chunks of 4 rows x 5 cols
    const int bid = blockIdx.y * 20 + blockIdx.x;
    const int xcd = bid & 7, idx = bid >> 3;          // idx in 0..79
    const int ch = idx / 20, w20 = idx % 20;
    const int rowBase = (xcd*4 + (w20 & 3)) * 256;
    const int colBase = (ch*5 + (w20 >> 2)) * 256;

    const int l = tid & 63, l15 = l & 15, quad = l >> 4;
    const int wv = tid >> 6, wr = wv >> 2, wc = wv & 3;   // 2 M-waves x 4 N-waves

    // read-side swizzle: logical k-group quad lives at kg = quad ^ ((row>>1)&3)
    const int fk   = (quad ^ ((l15 >> 1) & 3)) * 8;
    const int rowA = (wr*128 + l15)*32 + fk;              // + m*512 within slice
    const int rowB = (wc*64  + l15)*32 + fk;              // + n*512 within slice

    // stage-side inverse swizzle baked into the GLOBAL source column
    const int kOff = ((tid & 3) ^ ((tid >> 3) & 3)) * 8;
    const unsigned short* pA0 = A + (size_t)(rowBase + (tid >> 2)) * K_DIM + kOff;
    const unsigned short* pA1 = pA0 + (size_t)128 * K_DIM;
    const unsigned short* pB0 = B + (size_t)(colBase + (tid >> 2)) * K_DIM + kOff;
    const unsigned short* pB1 = pB0 + (size_t)128 * K_DIM;

    floatx4 acc[8][4] = {};
    short8 aF0[8], bF0[4], aF1[8], bF1[4];

    // prologue: slices 0,1,2 staged; slice 0 frags pre-read into buf0; slice 1 published.
    STAGE(0, 0); STAGE(1, 1); STAGE(2, 2);
    asm volatile("s_waitcnt vmcnt(8)" ::: "memory");   // slice 0 landed
    SBAR();
    READ_FRAGS(aF0, bF0, 0);
    asm volatile("s_waitcnt vmcnt(4)" ::: "memory");   // slice 1 landed
    SBAR();

    // 32 phases. Phase kk: issue ds_reads of slice kk+1 (just published) into the
    // spare reg buffer, issue STAGE(kk+3), then MFMA slice kk from the other buffer.
    for (int kk = 0; kk < 32; kk += 2){
        // even phase: MFMA buf0, read into buf1
        READ_FRAGS(aF1, bF1, (kk+1)&3);
        if (kk < 29) STAGE((kk+3)&3, kk+3);
        MFMA_ALL(aF0, bF0);
        if (kk < 29) asm volatile("s_waitcnt vmcnt(4)" ::: "memory");
        SBAR();
        // odd phase: MFMA buf1, read into buf0
        if (kk+1 < 31) READ_FRAGS(aF0, bF0, (kk+2)&3);
        if (kk+1 < 29) STAGE((kk+4)&3, kk+4);
        MFMA_ALL(aF1, bF1);
        if (kk+1 < 29)       asm volatile("s_waitcnt vmcnt(4)" ::: "memory");
        else if (kk+1 == 29) asm volatile("s_waitcnt vmcnt(0)" ::: "memory");
        SBAR();
    }

    // ---------------- fused epilogue ----------------
    const int gcol = colBase + wc*64;        // wave covers exactly one head (64 cols)
    const int seg  = gcol >> 10;             // 0=q, 1=k, 2=v, 3=alpha, 4=beta
    const int rbw  = rowBase + wr*128 + quad*4;
    if (seg < 2){
        const int h = (gcol >> 6) & 15;
        const int segOff = (seg == 0) ? 128 : 0;
        #pragma unroll
        for (int m = 0; m < 8; ++m){
            #pragma unroll
            for (int r = 0; r < 4; ++r){
                float ss = acc[m][0][r]*acc[m][0][r] + acc[m][1][r]*acc[m][1][r]
                         + acc[m][2][r]*acc[m][2][r] + acc[m][3][r]*acc[m][3][r];
                ss = red16(ss);
                const float rn = 1.f / fmaxf(sqrtf(ss), 1e-12f);
                const int row = rbw + m*16 + r;
                const size_t rec = (size_t)((row & 7)*16 + h)*1024 + (row >> 3);
                unsigned short* rp = (unsigned short*)(KQV + rec*512 + segOff);
                #pragma unroll
                for (int n = 0; n < 4; ++n)
                    rp[n*16 + l15] = f2bf(acc[m][n][r] * rn);
            }
        }
    } else if (seg == 2){
        const int h = (gcol >> 6) & 15;
        #pragma unroll
        for (int m = 0; m < 8; ++m){
            #pragma unroll
            for (int r = 0; r < 4; ++r){
                const int row = rbw + m*16 + r;
                const size_t rec = (size_t)((row & 7)*16 + h)*1024 + (row >> 3);
                float* vp = (float*)(KQV + rec*512 + 256);
                #pragma unroll
                for (int n = 0; n < 4; ++n)
                    vp[n*16 + l15] = acc[m][n][r];
            }
        }
    } else {
        const int isBeta = (seg == 4) ? 1 : 0;
        const float* bias = isBeta ? b_beta : b_alpha;
        const int gcol0 = gcol - (isBeta ? 4096 : 3072);
        const int hh = gcol0 >> 6;
        float bj[4];
        #pragma unroll
        for (int n = 0; n < 4; ++n) bj[n] = bias[gcol0 + n*16 + l15];
        #pragma unroll
        for (int m = 0; m < 8; ++m){
            #pragma unroll
            for (int r = 0; r < 4; ++r){
                float sum = 0.f;
                #pragma unroll
                for (int n = 0; n < 4; ++n) sum += sigf(acc[m][n][r] + bj[n]);
                sum = red16(sum);
                if (l15 == 0){
                    const int row = rbw + m*16 + r;
                    const int tt = row >> 3, bb = row & 7;
                    G[(((size_t)(bb*16 + hh)*1024 + tt))*2 + isBeta] = sum * (1.f/64.f);
                }
            }
        }
    }
}

// ---------------- Phase A: per-(bh,chunk) coefficients ----------------
__global__ __launch_bounds__(256) void phasea(const unsigned char* __restrict__ KQV,
                                              const float* __restrict__ G,
                                              unsigned short* __restrict__ Wtg,
                                              unsigned short* __restrict__ Ng,
                                              float* __restrict__ rg){
    __shared__ unsigned short sKa[64*PAD], sQa[64*PAD];
    __shared__ float sAB[128];
    __shared__ float sKK[4096];
    __shared__ float sR[64], sRi[64];

    const int unitIdx = blockIdx.x;
    const int bh = unitIdx >> 4, c = unitIdx & 15;
    const int tid = threadIdx.x;
    const int w = tid>>6, l = tid&63, l15 = l&15, quad = l>>4;
    const unsigned char* gRec = KQV + ((size_t)bh*1024 + c*64)*512;

    #pragma unroll
    for (int it=0; it<2; ++it){
        int flat = it*256 + tid, t = flat>>3, i8 = flat&7;
        float4 kv = *(const float4*)(gRec + t*512 + i8*16);
        float4 qv = *(const float4*)(gRec + t*512 + 128 + i8*16);
        *(float4*)&sKa[t*PAD + i8*8] = kv;
        *(float4*)&sQa[t*PAD + i8*8] = qv;
    }
    if (tid < 64){
        float2 ab = *(const float2*)(G + ((size_t)bh*1024 + c*64 + tid)*2);
        sAB[tid*2] = ab.x; sAB[tid*2+1] = ab.y;
    }
    __syncthreads();
    if (tid < 64){
        float p = sAB[tid*2];
        #pragma unroll
        for (int off=1; off<64; off<<=1){
            float y = __shfl_up(p, off);
            if (tid >= off) p *= y;
        }
        sR[tid] = p; sRi[tid] = 1.f/p;
    }
    __syncthreads();

    // KK (waves 0,1) / QK->N (waves 2,3)
    {
        const int isQK = w >> 1;
        const int tmb = (w & 1)*2;
        floatx4 acc[2][4] = {};
        #pragma unroll
        for (int ks=0; ks<2; ++ks){
            short8 aA[2]; short8 bB[4];
            #pragma unroll
            for (int i=0;i<2;++i)
                aA[i] = *(const short8*)&((isQK? sQa : sKa)[((tmb+i)*16 + l15)*PAD + ks*32 + quad*8]);
            #pragma unroll
            for (int j2=0;j2<4;++j2)
                bB[j2] = *(const short8*)&sKa[(j2*16 + l15)*PAD + ks*32 + quad*8];
            #pragma unroll
            for (int i=0;i<2;++i)
                #pragma unroll
                for (int j2=0;j2<4;++j2)
                    acc[i][j2] = __builtin_amdgcn_mfma_f32_16x16x32_bf16(aA[i], bB[j2], acc[i][j2], 0,0,0);
        }
        #pragma unroll
        for (int i=0;i<2;++i){
            #pragma unroll
            for (int j2=0;j2<4;++j2){
                #pragma unroll
                for (int r=0;r<4;++r){
                    int t = (tmb+i)*16 + quad*4 + r;
                    int s = j2*16 + l15;
                    float ratio = sR[t]*sRi[s];
                    if (!isQK){
                        sKK[t*64+s] = (s < t) ? sAB[t*2+1]*ratio*acc[i][j2][r] : 0.f;
                    } else {
                        float nv = (s <= t) ? ratio*acc[i][j2][r] : 0.f;
                        Ng[(size_t)unitIdx*4096 + t*64 + s] = f2bf(nv);
                    }
                }
            }
        }
    }
    __syncthreads();

    // X = (I+C)^-1, column-parallel forward substitution on wave 0.
    // Lane s keeps its own column X[0..63] in REGISTERS; sKK reads are
    // wave-uniform broadcasts (float4).
    if (tid < 64){
        const int s = tid;
        float X[64];
        X[0] = (s == 0) ? 1.f : 0.f;
        #pragma unroll
        for (int t=1; t<64; ++t){
            float a0 = 0.f, a1 = 0.f;
            const float* row = &sKK[t*64];
            int r = 0;
            #pragma unroll
            for (; r+4 <= t; r += 4){
                float4 cv = *(const float4*)&row[r];
                a0 += cv.x * X[r];
                a1 += cv.y * X[r+1];
                a0 += cv.z * X[r+2];
                a1 += cv.w * X[r+3];
            }
            #pragma unroll
            for (; r+1 < t; r += 2){
                a0 += row[r]   * X[r];
                a1 += row[r+1] * X[r+1];
            }
            if (r < t) a0 += row[r] * X[r];
            X[t] = (s == t) ? 1.f : -(a0+a1);
        }
        const float be = sAB[s*2+1];
        #pragma unroll
        for (int t=0; t<64; ++t)
            Wtg[(size_t)unitIdx*4096 + t*64 + s] = f2bf(X[t]*be);
        rg[(size_t)unitIdx*64 + s] = sR[s];
    }
}

// ---------------- Phase B: sequential chunk scan via MFMA ----------------
// 256 blocks, 512 threads = 8 waves: wt = w&3 (t-tile), wg = w>>2 (d-quarter).
// XCD-PAIRING DECODE: the two half-blocks of one bh get IDs differing by 8
// -> same id%8 -> same XCD under round-robin dispatch, adjacent in time.
// Their identical K/Q/Wt/N reads then hit that XCD's L2 instead of HBM.
__global__ __launch_bounds__(512) void chunk_scan(const unsigned char* __restrict__ KQV,
                                                  const unsigned short* __restrict__ Wtg,
                                                  const unsigned short* __restrict__ Ng,
                                                  const float* __restrict__ rg,
                                                  const float* __restrict__ S0g,
                                                  float* __restrict__ out){
    __shared__ unsigned short sK[64*PAD], sQ[64*PAD], sWt[64*PAD];
    __shared__ unsigned short sN[2][64*PAD];
    __shared__ unsigned short sUt[32*PAD];
    __shared__ unsigned short sKtU[32*PAD];   // RHS^T (d2-local rows 0..31)
    __shared__ unsigned short sKt2[64*PAD];   // scaled K~^T (d_k rows 0..63)
    __shared__ unsigned short sS0b[32*PAD];
    __shared__ float sr[2][64];

    const int id = blockIdx.x;
    const int xcdp = id & 7, grp = id >> 3;
    const int half = grp & 1;
    const int bh = ((grp >> 1) << 3) | xcdp;   // bijective: 16 pair-groups x 8 xcd
    const int b = bh >> 4, h = bh & 15;
    const int tid = threadIdx.x;
    const int w = tid >> 6, l = tid & 63, l15 = l & 15, quad = l >> 4;
    const int wt = w & 3, wg = w >> 2;
    const int t0 = wt*16 + quad*4;
    const int dq = wg*16;
    const int d2base = dq + quad*4;
    const unsigned char* gRec = KQV + (size_t)bh * (1024*512);
    const size_t outBase = (size_t)b*1024 + h*64 + half*32;

    float4 kst, qst, wst, nst;
    float rst = 0.f;
    float vCur[4], vNext[4];
    floatx4 Sreg;

    // prologue: chunk 0
    {
        const int unit = bh*16;
        const int t = tid>>3, i8 = tid&7;
        kst = *(const float4*)(gRec + t*512 +       i8*16);
        qst = *(const float4*)(gRec + t*512 + 128 + i8*16);
        wst = *(const float4*)((const unsigned char*)Wtg + (size_t)unit*8192 + (size_t)tid*16);
        nst = *(const float4*)((const unsigned char*)Ng  + (size_t)unit*8192 + (size_t)tid*16);
        if (tid < 64) rst = rg[(size_t)unit*64 + tid];
        #pragma unroll
        for (int r=0; r<4; ++r)
            vCur[r] = *(const float*)(gRec + (t0+r)*512 + 256 + (half*32 + dq + l15)*4);
        #pragma unroll
        for (int r=0;r<4;++r)
            Sreg[r] = S0g[(size_t)bh*4096 + (half*32 + d2base + r)*64 + wt*16 + l15];
        *(float4*)&sK[t*PAD + i8*8]    = kst;
        *(float4*)&sQ[t*PAD + i8*8]    = qst;
        *(float4*)&sWt[t*PAD + i8*8]   = wst;
        *(float4*)&sN[0][t*PAD + i8*8] = nst;
        if (tid < 64) sr[0][tid] = rst;
        #pragma unroll
        for (int r=0;r<4;++r)
            sS0b[(d2base+r)*PAD + wt*16 + l15] = f2bf(Sreg[r]);
    }
    __syncthreads();

    for (int c=0; c<16; ++c){
        const int buf = c & 1;
        if (c < 15){
            const int unit = bh*16 + c + 1;
            const unsigned char* gRecN = gRec + (size_t)(c+1)*64*512;
            const int t = tid>>3, i8 = tid&7;
            kst = *(const float4*)(gRecN + t*512 +       i8*16);
            qst = *(const float4*)(gRecN + t*512 + 128 + i8*16);
            wst = *(const float4*)((const unsigned char*)Wtg + (size_t)unit*8192 + (size_t)tid*16);
            nst = *(const float4*)((const unsigned char*)Ng  + (size_t)unit*8192 + (size_t)tid*16);
            if (tid < 64) rst = rg[(size_t)unit*64 + tid];
            #pragma unroll
            for (int r=0;r<4;++r)
                vNext[r] = *(const float*)(gRecN + (t0+r)*512 + 256 + (half*32 + dq + l15)*4);
        }

        // stage 1: PT = K*S0^T, OB = Q*S0^T; RHS^T write; scaled-K~^T build (indep).
        floatx4 accPT = {}; floatx4 accOB = {};
        #pragma unroll
        for (int ks=0; ks<2; ++ks){
            short8 aK = *(const short8*)&sK[(wt*16 + l15)*PAD + ks*32 + quad*8];
            short8 aQ = *(const short8*)&sQ[(wt*16 + l15)*PAD + ks*32 + quad*8];
            short8 bS = *(const short8*)&sS0b[(dq + l15)*PAD + ks*32 + quad*8];
            accPT = __builtin_amdgcn_mfma_f32_16x16x32_bf16(aK, bS, accPT, 0,0,0);
            accOB = __builtin_amdgcn_mfma_f32_16x16x32_bf16(aQ, bS, accOB, 0,0,0);
        }
        float r4[4];
        #pragma unroll
        for (int r=0;r<4;++r) r4[r] = sr[buf][t0+r];
        {
            float x0 = vCur[0] - r4[0]*accPT[0];
            float x1 = vCur[1] - r4[1]*accPT[1];
            float x2 = vCur[2] - r4[2]*accPT[2];
            float x3 = vCur[3] - r4[3]*accPT[3];
            uint2 uu;
            uu.x = (unsigned)f2bf(x0) | ((unsigned)f2bf(x1)<<16);
            uu.y = (unsigned)f2bf(x2) | ((unsigned)f2bf(x3)<<16);
            *(uint2*)&sKtU[(dq + l15)*PAD + t0] = uu;     // RHS^T[d2][t]
        }
        {   // scaled K~^T: reads sK, sr only (stable since chunk start)
            const float rl = sr[buf][63];
            const int e = tid >> 3, sb = (tid & 7)*8;
            #pragma unroll
            for (int j2=0; j2<8; ++j2){
                int s = sb + j2;
                float kv = __uint_as_float((unsigned)sK[s*PAD + e] << 16);
                sKt2[e*PAD + s] = f2bf(kv * (rl / sr[buf][s]));
            }
        }
        __syncthreads();   // A: RHS^T + K~^T published

        // stage 2: U = Wt * RHS^T; write U^T
        floatx4 accU = {};
        #pragma unroll
        for (int ks=0; ks<2; ++ks){
            short8 aW = *(const short8*)&sWt[(wt*16 + l15)*PAD + ks*32 + quad*8];
            short8 bR = *(const short8*)&sKtU[(dq + l15)*PAD + ks*32 + quad*8];
            accU = __builtin_amdgcn_mfma_f32_16x16x32_bf16(aW, bR, accU, 0,0,0);
        }
        {
            uint2 uu;
            uu.x = (unsigned)f2bf(accU[0]) | ((unsigned)f2bf(accU[1])<<16);
            uu.y = (unsigned)f2bf(accU[2]) | ((unsigned)f2bf(accU[3])<<16);
            *(uint2*)&sUt[(dq + l15)*PAD + t0] = uu;
        }
        __syncthreads();   // B: U^T published

        // stage 3: O = diag(r)*OB + N*U^T ;  S = rl*S0 + U^T * K~^T
        floatx4 accO;
        #pragma unroll
        for (int r=0;r<4;++r) accO[r] = r4[r]*accOB[r];
        #pragma unroll
        for (int ks=0; ks<2; ++ks){
            short8 aN = *(const short8*)&sN[buf][(wt*16 + l15)*PAD + ks*32 + quad*8];
            short8 bU = *(const short8*)&sUt[(dq + l15)*PAD + ks*32 + quad*8];
            accO = __builtin_amdgcn_mfma_f32_16x16x32_bf16(aN, bU, accO, 0,0,0);
        }
        const float rl = sr[buf][63];
        floatx4 accS;
        #pragma unroll
        for (int r=0;r<4;++r) accS[r] = rl*Sreg[r];
        #pragma unroll
        for (int ks=0; ks<2; ++ks){
            short8 aU = *(const short8*)&sUt[(dq + l15)*PAD + ks*32 + quad*8];
            short8 bK = *(const short8*)&sKt2[(wt*16 + l15)*PAD + ks*32 + quad*8];
            accS = __builtin_amdgcn_mfma_f32_16x16x32_bf16(aU, bK, accS, 0,0,0);
        }
        Sreg = accS;

        #pragma unroll
        for (int r=0;r<4;++r)
            out[(size_t)(c*64 + t0 + r)*8192 + outBase + dq + l15] = accO[r];
        #pragma unroll
        for (int r=0;r<4;++r)
            sS0b[(d2base + r)*PAD + wt*16 + l15] = f2bf(Sreg[r]);

        if (c < 15){
            const int t = tid>>3, i8 = tid&7;
            *(float4*)&sK[t*PAD + i8*8]         = kst;
            *(float4*)&sQ[t*PAD + i8*8]         = qst;
            *(float4*)&sWt[t*PAD + i8*8]        = wst;
            *(float4*)&sN[buf^1][t*PAD + i8*8]  = nst;
            if (tid < 64) sr[buf^1][tid] = rst;
            #pragma unroll
            for (int r=0;r<4;++r) vCur[r] = vNext[r];
        }
        __syncthreads();   // C: end of chunk
    }

    // final state
    #pragma unroll
    for (int r=0;r<4;++r)
        out[(size_t)8388608 + (size_t)bh*4096 + (half*32 + d2base + r)*64 + wt*16 + l15] = Sreg[r];
}

extern "C" void kernel_launch(void* const* d_in, const int* in_sizes, int n_in,
                              void* d_out, int out_size, void* d_ws, size_t ws_size,
                              hipStream_t stream){
    const float* x  = (const float*)d_in[0];
    const float* S0 = (const float*)d_in[1];
    const float* Wq = (const float*)d_in[2];
    const float* Wk = (const float*)d_in[3];
    const float* Wv = (const float*)d_in[4];
    const float* Wa = (const float*)d_in[5];
    const float* ba = (const float*)d_in[6];
    const float* Wb = (const float*)d_in[7];
    const float* bb = (const float*)d_in[8];
    float* out = (float*)d_out;

    char* ws = (char*)d_ws;
    unsigned short* Abf = (unsigned short*)ws;                    // 16,777,216
    unsigned short* Bbf = (unsigned short*)(ws + 16777216);       // 10,485,760
    unsigned char*  KQV = (unsigned char*) (ws + 27262976);       // 67,108,864 (128*1024*512)
    float*          G   = (float*)         (ws + 94371840);       //  1,048,576
    unsigned short* Wtg = (unsigned short*)(ws + 95420416);       // 16,777,216 (2048*4096 bf16)
    unsigned short* Ng  = (unsigned short*)(ws + 112197632);      // 16,777,216
    float*          rg  = (float*)         (ws + 128974848);      //    524,288  -> end 129,499,136

    cvt_bf16<<<2048, 256, 0, stream>>>(x, Abf, (M_ROWS*K_DIM)/4);
    cvt_w<<<5120, 256, 0, stream>>>(Wq, Wk, Wv, Wa, Wb, Bbf);

    dim3 gg(N_COLS/256, M_ROWS/256);   // 20 x 32 = 640 blocks, 512 threads
    gemm_bt<<<gg, 512, 0, stream>>>(Abf, Bbf, KQV, G, ba, bb);

    phasea<<<2048, 256, 0, stream>>>(KQV, G, Wtg, Ng, rg);

    chunk_scan<<<256, 512, 0, stream>>>(KQV, Wtg, Ng, rg, S0, out);
}

// Round 12
// 280.311 us; speedup vs baseline: 1.0437x; 1.0054x over previous
//
#include <hip/hip_runtime.h>
#include <hip/hip_bf16.h>
#include <math.h>

#define T_DIM 1024
#define B_DIM 8
#define D_DIM 1024
#define H_DIM 16
#define DH 64
#define M_ROWS 8192          // T*B
#define N_COLS 5120          // 5*D
#define K_DIM 1024
#define PAD 72               // padded bf16 row length (144 B): b128-aligned, conflict-free

typedef __attribute__((ext_vector_type(8))) short short8;
typedef __attribute__((ext_vector_type(4))) float floatx4;

static __device__ __forceinline__ unsigned short f2bf(float f){
    unsigned int u = __float_as_uint(f);
    u += 0x7fff + ((u >> 16) & 1);          // RNE
    return (unsigned short)(u >> 16);
}
static __device__ __forceinline__ float sigf(float x){
    return 1.f / (1.f + __expf(-x));
}

// DPP butterfly adds on VALU pipe
#define DPPADD(x, ctrl) ((x) + __int_as_float(__builtin_amdgcn_update_dpp(0, __float_as_int(x), (ctrl), 0xF, 0xF, true)))
static __device__ __forceinline__ float red16(float x){
    x = DPPADD(x, 0xB1); x = DPPADD(x, 0x4E); x = DPPADD(x, 0x141); x = DPPADD(x, 0x140); return x;
}

// ---------------- fused fp32 -> bf16 conversion (x + all 5 weights) ----------------
#define X_F4   2097152                     // 8192*1024/4
#define ALL_F4 3407872                     // X_F4 + 5*1024*1024/4
__global__ void cvt_all(const float* __restrict__ x,
                        const float* __restrict__ w0, const float* __restrict__ w1,
                        const float* __restrict__ w2, const float* __restrict__ w3,
                        const float* __restrict__ w4,
                        unsigned short* __restrict__ Abf,
                        unsigned short* __restrict__ Bbf){
    int i = blockIdx.x*blockDim.x + threadIdx.x;
    int stride = gridDim.x*blockDim.x;
    for (; i < ALL_F4; i += stride){
        float4 f; ushort4* dp;
        if (i < X_F4){
            f  = ((const float4*)x)[i];
            dp = &((ushort4*)Abf)[i];
        } else {
            int j = i - X_F4;
            int seg = j >> 18, off = j & 262143;
            const float* src = (seg==0)?w0:(seg==1)?w1:(seg==2)?w2:(seg==3)?w3:w4;
            f  = ((const float4*)src)[off];
            dp = &((ushort4*)Bbf)[j];
        }
        ushort4 o;
        o.x = f2bf(f.x); o.y = f2bf(f.y); o.z = f2bf(f.z); o.w = f2bf(f.w);
        *dp = o;
    }
}

// ---------------- NT GEMM + fused epilogue (256^2, 8 waves, ring-4) ----------------
// KQV record per (bh,t): 512 B = [khat bf16 x64 | qhat bf16 x64 | v fp32 x64]
// gates -> G[bh][t] = {alpha, beta} fp32
#define GLD16(g, l) __builtin_amdgcn_global_load_lds(                         \
    (const __attribute__((address_space(1))) void*)(g),                       \
    (__attribute__((address_space(3))) void*)(l), 16, 0, 0)

#define SBAR() do { asm volatile("" ::: "memory"); __builtin_amdgcn_s_barrier(); asm volatile("" ::: "memory"); } while(0)

// stage one k-slice (256 rows x 32 k for A and B) into ring slot (512 threads -> 4 GLD16)
#define STAGE(slot, kk) do {                                                  \
    GLD16(pA0 + (kk)*32, &As[slot][tid*8]);                                   \
    GLD16(pA1 + (kk)*32, &As[slot][4096 + tid*8]);                            \
    GLD16(pB0 + (kk)*32, &Bs[slot][tid*8]);                                   \
    GLD16(pB1 + (kk)*32, &Bs[slot][4096 + tid*8]); } while(0)

#define READ_FRAGS(aF, bF, slot) do {                                         \
    aF[0] = *(const short8*)&As[slot][rowA];                                  \
    _Pragma("unroll")                                                         \
    for (int n = 0; n < 4; ++n) bF[n] = *(const short8*)&Bs[slot][rowB + n*512]; \
    _Pragma("unroll")                                                         \
    for (int m = 1; m < 8; ++m) aF[m] = *(const short8*)&As[slot][rowA + m*512]; \
} while(0)

#define MFMA_ALL(aF, bF) do {                                                 \
    __builtin_amdgcn_s_setprio(1);                                            \
    _Pragma("unroll")                                                         \
    for (int m = 0; m < 8; ++m)                                               \
        _Pragma("unroll")                                                     \
        for (int n = 0; n < 4; ++n)                                           \
            acc[m][n] = __builtin_amdgcn_mfma_f32_16x16x32_bf16(aF[m], bF[n], acc[m][n], 0,0,0); \
    __builtin_amdgcn_s_setprio(0);                                            \
} while(0)

__global__ __launch_bounds__(512, 2) void gemm_bt(const unsigned short* __restrict__ A,
                                                  const unsigned short* __restrict__ B,
                                                  unsigned char* __restrict__ KQV,
                                                  float* __restrict__ G,
                                                  const float* __restrict__ b_alpha,
                                                  const float* __restrict__ b_beta){
    // ring of 4 k-slices per operand, 16 KiB each (256 rows x 32 k bf16), XOR-swizzled
    __shared__ unsigned short As[4][8192];
    __shared__ unsigned short Bs[4][8192];
    const int tid = threadIdx.x;

    // XCD-aware bijective swizzle over 640 blocks; within-XCD chunks of 4 rows x 5 cols
    const int bid = blockIdx.y * 20 + blockIdx.x;
    const int xcd = bid & 7, idx = bid >> 3;          // idx in 0..79
    const int ch = idx / 20, w20 = idx % 20;
    const int rowBase = (xcd*4 + (w20 & 3)) * 256;
    const int colBase = (ch*5 + (w20 >> 2)) * 256;

    const int l = tid & 63, l15 = l & 15, quad = l >> 4;
    const int wv = tid >> 6, wr = wv >> 2, wc = wv & 3;   // 2 M-waves x 4 N-waves

    // read-side swizzle: logical k-group quad lives at kg = quad ^ ((row>>1)&3)
    const int fk   = (quad ^ ((l15 >> 1) & 3)) * 8;
    const int rowA = (wr*128 + l15)*32 + fk;              // + m*512 within slice
    const int rowB = (wc*64  + l15)*32 + fk;              // + n*512 within slice

    // stage-side inverse swizzle baked into the GLOBAL source column
    const int kOff = ((tid & 3) ^ ((tid >> 3) & 3)) * 8;
    const unsigned short* pA0 = A + (size_t)(rowBase + (tid >> 2)) * K_DIM + kOff;
    const unsigned short* pA1 = pA0 + (size_t)128 * K_DIM;
    const unsigned short* pB0 = B + (size_t)(colBase + (tid >> 2)) * K_DIM + kOff;
    const unsigned short* pB1 = pB0 + (size_t)128 * K_DIM;

    floatx4 acc[8][4] = {};
    short8 aF0[8], bF0[4], aF1[8], bF1[4];

    // prologue: slices 0,1,2 staged; slice 0 frags pre-read into buf0; slice 1 published.
    STAGE(0, 0); STAGE(1, 1); STAGE(2, 2);
    asm volatile("s_waitcnt vmcnt(8)" ::: "memory");   // slice 0 landed
    SBAR();
    READ_FRAGS(aF0, bF0, 0);
    asm volatile("s_waitcnt vmcnt(4)" ::: "memory");   // slice 1 landed
    SBAR();

    // 32 phases. Phase kk: issue ds_reads of slice kk+1 (just published) into the
    // spare reg buffer, issue STAGE(kk+3), then MFMA slice kk from the other buffer.
    for (int kk = 0; kk < 32; kk += 2){
        // even phase: MFMA buf0, read into buf1
        READ_FRAGS(aF1, bF1, (kk+1)&3);
        if (kk < 29) STAGE((kk+3)&3, kk+3);
        MFMA_ALL(aF0, bF0);
        if (kk < 29) asm volatile("s_waitcnt vmcnt(4)" ::: "memory");
        SBAR();
        // odd phase: MFMA buf1, read into buf0
        if (kk+1 < 31) READ_FRAGS(aF0, bF0, (kk+2)&3);
        if (kk+1 < 29) STAGE((kk+4)&3, kk+4);
        MFMA_ALL(aF1, bF1);
        if (kk+1 < 29)       asm volatile("s_waitcnt vmcnt(4)" ::: "memory");
        else if (kk+1 == 29) asm volatile("s_waitcnt vmcnt(0)" ::: "memory");
        SBAR();
    }

    // ---------------- fused epilogue ----------------
    const int gcol = colBase + wc*64;        // wave covers exactly one head (64 cols)
    const int seg  = gcol >> 10;             // 0=q, 1=k, 2=v, 3=alpha, 4=beta
    const int rbw  = rowBase + wr*128 + quad*4;
    if (seg < 2){
        const int h = (gcol >> 6) & 15;
        const int segOff = (seg == 0) ? 128 : 0;
        #pragma unroll
        for (int m = 0; m < 8; ++m){
            #pragma unroll
            for (int r = 0; r < 4; ++r){
                float ss = acc[m][0][r]*acc[m][0][r] + acc[m][1][r]*acc[m][1][r]
                         + acc[m][2][r]*acc[m][2][r] + acc[m][3][r]*acc[m][3][r];
                ss = red16(ss);
                const float rn = 1.f / fmaxf(sqrtf(ss), 1e-12f);
                const int row = rbw + m*16 + r;
                const size_t rec = (size_t)((row & 7)*16 + h)*1024 + (row >> 3);
                unsigned short* rp = (unsigned short*)(KQV + rec*512 + segOff);
                #pragma unroll
                for (int n = 0; n < 4; ++n)
                    rp[n*16 + l15] = f2bf(acc[m][n][r] * rn);
            }
        }
    } else if (seg == 2){
        const int h = (gcol >> 6) & 15;
        #pragma unroll
        for (int m = 0; m < 8; ++m){
            #pragma unroll
            for (int r = 0; r < 4; ++r){
                const int row = rbw + m*16 + r;
                const size_t rec = (size_t)((row & 7)*16 + h)*1024 + (row >> 3);
                float* vp = (float*)(KQV + rec*512 + 256);
                #pragma unroll
                for (int n = 0; n < 4; ++n)
                    vp[n*16 + l15] = acc[m][n][r];
            }
        }
    } else {
        const int isBeta = (seg == 4) ? 1 : 0;
        const float* bias = isBeta ? b_beta : b_alpha;
        const int gcol0 = gcol - (isBeta ? 4096 : 3072);
        const int hh = gcol0 >> 6;
        float bj[4];
        #pragma unroll
        for (int n = 0; n < 4; ++n) bj[n] = bias[gcol0 + n*16 + l15];
        #pragma unroll
        for (int m = 0; m < 8; ++m){
            #pragma unroll
            for (int r = 0; r < 4; ++r){
                float sum = 0.f;
                #pragma unroll
                for (int n = 0; n < 4; ++n) sum += sigf(acc[m][n][r] + bj[n]);
                sum = red16(sum);
                if (l15 == 0){
                    const int row = rbw + m*16 + r;
                    const int tt = row >> 3, bb = row & 7;
                    G[(((size_t)(bb*16 + hh)*1024 + tt))*2 + isBeta] = sum * (1.f/64.f);
                }
            }
        }
    }
}

// ---------------- Phase A: per-(bh,chunk) coefficients ----------------
// Substitution wave chosen by unitIdx&3 so co-resident blocks' serial
// sections land on DIFFERENT SIMDs (block wave w -> SIMD w; 4 blocks/CU).
__global__ __launch_bounds__(256) void phasea(const unsigned char* __restrict__ KQV,
                                              const float* __restrict__ G,
                                              unsigned short* __restrict__ Wtg,
                                              unsigned short* __restrict__ Ng,
                                              float* __restrict__ rg){
    __shared__ unsigned short sKa[64*PAD], sQa[64*PAD];
    __shared__ float sAB[128];
    __shared__ float sKK[4096];
    __shared__ float sR[64], sRi[64];

    const int unitIdx = blockIdx.x;
    const int bh = unitIdx >> 4, c = unitIdx & 15;
    const int tid = threadIdx.x;
    const int w = tid>>6, l = tid&63, l15 = l&15, quad = l>>4;
    const unsigned char* gRec = KQV + ((size_t)bh*1024 + c*64)*512;

    #pragma unroll
    for (int it=0; it<2; ++it){
        int flat = it*256 + tid, t = flat>>3, i8 = flat&7;
        float4 kv = *(const float4*)(gRec + t*512 + i8*16);
        float4 qv = *(const float4*)(gRec + t*512 + 128 + i8*16);
        *(float4*)&sKa[t*PAD + i8*8] = kv;
        *(float4*)&sQa[t*PAD + i8*8] = qv;
    }
    if (tid < 64){
        float2 ab = *(const float2*)(G + ((size_t)bh*1024 + c*64 + tid)*2);
        sAB[tid*2] = ab.x; sAB[tid*2+1] = ab.y;
    }
    __syncthreads();
    if (tid < 64){
        float p = sAB[tid*2];
        #pragma unroll
        for (int off=1; off<64; off<<=1){
            float y = __shfl_up(p, off);
            if (tid >= off) p *= y;
        }
        sR[tid] = p; sRi[tid] = 1.f/p;
    }
    __syncthreads();

    // KK (waves 0,1) / QK->N (waves 2,3)
    {
        const int isQK = w >> 1;
        const int tmb = (w & 1)*2;
        floatx4 acc[2][4] = {};
        #pragma unroll
        for (int ks=0; ks<2; ++ks){
            short8 aA[2]; short8 bB[4];
            #pragma unroll
            for (int i=0;i<2;++i)
                aA[i] = *(const short8*)&((isQK? sQa : sKa)[((tmb+i)*16 + l15)*PAD + ks*32 + quad*8]);
            #pragma unroll
            for (int j2=0;j2<4;++j2)
                bB[j2] = *(const short8*)&sKa[(j2*16 + l15)*PAD + ks*32 + quad*8];
            #pragma unroll
            for (int i=0;i<2;++i)
                #pragma unroll
                for (int j2=0;j2<4;++j2)
                    acc[i][j2] = __builtin_amdgcn_mfma_f32_16x16x32_bf16(aA[i], bB[j2], acc[i][j2], 0,0,0);
        }
        #pragma unroll
        for (int i=0;i<2;++i){
            #pragma unroll
            for (int j2=0;j2<4;++j2){
                #pragma unroll
                for (int r=0;r<4;++r){
                    int t = (tmb+i)*16 + quad*4 + r;
                    int s = j2*16 + l15;
                    float ratio = sR[t]*sRi[s];
                    if (!isQK){
                        sKK[t*64+s] = (s < t) ? sAB[t*2+1]*ratio*acc[i][j2][r] : 0.f;
                    } else {
                        float nv = (s <= t) ? ratio*acc[i][j2][r] : 0.f;
                        Ng[(size_t)unitIdx*4096 + t*64 + s] = f2bf(nv);
                    }
                }
            }
        }
    }
    __syncthreads();

    // X = (I+C)^-1, column-parallel forward substitution on wave (unitIdx&3).
    // Lane s keeps its own column X[0..63] in REGISTERS; sKK reads are
    // wave-uniform broadcasts (float4).
    if (w == (unitIdx & 3)){
        const int s = l;
        float X[64];
        X[0] = (s == 0) ? 1.f : 0.f;
        #pragma unroll
        for (int t=1; t<64; ++t){
            float a0 = 0.f, a1 = 0.f;
            const float* row = &sKK[t*64];
            int r = 0;
            #pragma unroll
            for (; r+4 <= t; r += 4){
                float4 cv = *(const float4*)&row[r];
                a0 += cv.x * X[r];
                a1 += cv.y * X[r+1];
                a0 += cv.z * X[r+2];
                a1 += cv.w * X[r+3];
            }
            #pragma unroll
            for (; r+1 < t; r += 2){
                a0 += row[r]   * X[r];
                a1 += row[r+1] * X[r+1];
            }
            if (r < t) a0 += row[r] * X[r];
            X[t] = (s == t) ? 1.f : -(a0+a1);
        }
        const float be = sAB[s*2+1];
        #pragma unroll
        for (int t=0; t<64; ++t)
            Wtg[(size_t)unitIdx*4096 + t*64 + s] = f2bf(X[t]*be);
        rg[(size_t)unitIdx*64 + s] = sR[s];
    }
}

// ---------------- Phase B: sequential chunk scan via MFMA ----------------
// 256 blocks, 512 threads = 8 waves: wt = w&3 (t-tile), wg = w>>2 (d-quarter).
// XCD-PAIRING DECODE: the two half-blocks of one bh get IDs differing by 8
// -> same id%8 -> same XCD under round-robin dispatch, adjacent in time.
// Their identical K/Q/Wt/N reads then hit that XCD's L2 instead of HBM.
__global__ __launch_bounds__(512) void chunk_scan(const unsigned char* __restrict__ KQV,
                                                  const unsigned short* __restrict__ Wtg,
                                                  const unsigned short* __restrict__ Ng,
                                                  const float* __restrict__ rg,
                                                  const float* __restrict__ S0g,
                                                  float* __restrict__ out){
    __shared__ unsigned short sK[64*PAD], sQ[64*PAD], sWt[64*PAD];
    __shared__ unsigned short sN[2][64*PAD];
    __shared__ unsigned short sUt[32*PAD];
    __shared__ unsigned short sKtU[32*PAD];   // RHS^T (d2-local rows 0..31)
    __shared__ unsigned short sKt2[64*PAD];   // scaled K~^T (d_k rows 0..63)
    __shared__ unsigned short sS0b[32*PAD];
    __shared__ float sr[2][64];

    const int id = blockIdx.x;
    const int xcdp = id & 7, grp = id >> 3;
    const int half = grp & 1;
    const int bh = ((grp >> 1) << 3) | xcdp;   // bijective: 16 pair-groups x 8 xcd
    const int b = bh >> 4, h = bh & 15;
    const int tid = threadIdx.x;
    const int w = tid >> 6, l = tid & 63, l15 = l & 15, quad = l >> 4;
    const int wt = w & 3, wg = w >> 2;
    const int t0 = wt*16 + quad*4;
    const int dq = wg*16;
    const int d2base = dq + quad*4;
    const unsigned char* gRec = KQV + (size_t)bh * (1024*512);
    const size_t outBase = (size_t)b*1024 + h*64 + half*32;

    float4 kst, qst, wst, nst;
    float rst = 0.f;
    float vCur[4], vNext[4];
    floatx4 Sreg;

    // prologue: chunk 0
    {
        const int unit = bh*16;
        const int t = tid>>3, i8 = tid&7;
        kst = *(const float4*)(gRec + t*512 +       i8*16);
        qst = *(const float4*)(gRec + t*512 + 128 + i8*16);
        wst = *(const float4*)((const unsigned char*)Wtg + (size_t)unit*8192 + (size_t)tid*16);
        nst = *(const float4*)((const unsigned char*)Ng  + (size_t)unit*8192 + (size_t)tid*16);
        if (tid < 64) rst = rg[(size_t)unit*64 + tid];
        #pragma unroll
        for (int r=0; r<4; ++r)
            vCur[r] = *(const float*)(gRec + (t0+r)*512 + 256 + (half*32 + dq + l15)*4);
        #pragma unroll
        for (int r=0;r<4;++r)
            Sreg[r] = S0g[(size_t)bh*4096 + (half*32 + d2base + r)*64 + wt*16 + l15];
        *(float4*)&sK[t*PAD + i8*8]    = kst;
        *(float4*)&sQ[t*PAD + i8*8]    = qst;
        *(float4*)&sWt[t*PAD + i8*8]   = wst;
        *(float4*)&sN[0][t*PAD + i8*8] = nst;
        if (tid < 64) sr[0][tid] = rst;
        #pragma unroll
        for (int r=0;r<4;++r)
            sS0b[(d2base+r)*PAD + wt*16 + l15] = f2bf(Sreg[r]);
    }
    __syncthreads();

    for (int c=0; c<16; ++c){
        const int buf = c & 1;
        if (c < 15){
            const int unit = bh*16 + c + 1;
            const unsigned char* gRecN = gRec + (size_t)(c+1)*64*512;
            const int t = tid>>3, i8 = tid&7;
            kst = *(const float4*)(gRecN + t*512 +       i8*16);
            qst = *(const float4*)(gRecN + t*512 + 128 + i8*16);
            wst = *(const float4*)((const unsigned char*)Wtg + (size_t)unit*8192 + (size_t)tid*16);
            nst = *(const float4*)((const unsigned char*)Ng  + (size_t)unit*8192 + (size_t)tid*16);
            if (tid < 64) rst = rg[(size_t)unit*64 + tid];
            #pragma unroll
            for (int r=0;r<4;++r)
                vNext[r] = *(const float*)(gRecN + (t0+r)*512 + 256 + (half*32 + dq + l15)*4);
        }

        // stage 1: PT = K*S0^T, OB = Q*S0^T; RHS^T write; scaled-K~^T build (indep).
        floatx4 accPT = {}; floatx4 accOB = {};
        #pragma unroll
        for (int ks=0; ks<2; ++ks){
            short8 aK = *(const short8*)&sK[(wt*16 + l15)*PAD + ks*32 + quad*8];
            short8 aQ = *(const short8*)&sQ[(wt*16 + l15)*PAD + ks*32 + quad*8];
            short8 bS = *(const short8*)&sS0b[(dq + l15)*PAD + ks*32 + quad*8];
            accPT = __builtin_amdgcn_mfma_f32_16x16x32_bf16(aK, bS, accPT, 0,0,0);
            accOB = __builtin_amdgcn_mfma_f32_16x16x32_bf16(aQ, bS, accOB, 0,0,0);
        }
        float r4[4];
        #pragma unroll
        for (int r=0;r<4;++r) r4[r] = sr[buf][t0+r];
        {
            float x0 = vCur[0] - r4[0]*accPT[0];
            float x1 = vCur[1] - r4[1]*accPT[1];
            float x2 = vCur[2] - r4[2]*accPT[2];
            float x3 = vCur[3] - r4[3]*accPT[3];
            uint2 uu;
            uu.x = (unsigned)f2bf(x0) | ((unsigned)f2bf(x1)<<16);
            uu.y = (unsigned)f2bf(x2) | ((unsigned)f2bf(x3)<<16);
            *(uint2*)&sKtU[(dq + l15)*PAD + t0] = uu;     // RHS^T[d2][t]
        }
        {   // scaled K~^T: reads sK, sr only (stable since chunk start)
            const float rl = sr[buf][63];
            const int e = tid >> 3, sb = (tid & 7)*8;
            #pragma unroll
            for (int j2=0; j2<8; ++j2){
                int s = sb + j2;
                float kv = __uint_as_float((unsigned)sK[s*PAD + e] << 16);
                sKt2[e*PAD + s] = f2bf(kv * (rl / sr[buf][s]));
            }
        }
        __syncthreads();   // A: RHS^T + K~^T published

        // stage 2: U = Wt * RHS^T; write U^T
        floatx4 accU = {};
        #pragma unroll
        for (int ks=0; ks<2; ++ks){
            short8 aW = *(const short8*)&sWt[(wt*16 + l15)*PAD + ks*32 + quad*8];
            short8 bR = *(const short8*)&sKtU[(dq + l15)*PAD + ks*32 + quad*8];
            accU = __builtin_amdgcn_mfma_f32_16x16x32_bf16(aW, bR, accU, 0,0,0);
        }
        {
            uint2 uu;
            uu.x = (unsigned)f2bf(accU[0]) | ((unsigned)f2bf(accU[1])<<16);
            uu.y = (unsigned)f2bf(accU[2]) | ((unsigned)f2bf(accU[3])<<16);
            *(uint2*)&sUt[(dq + l15)*PAD + t0] = uu;
        }
        __syncthreads();   // B: U^T published

        // stage 3: O = diag(r)*OB + N*U^T ;  S = rl*S0 + U^T * K~^T
        floatx4 accO;
        #pragma unroll
        for (int r=0;r<4;++r) accO[r] = r4[r]*accOB[r];
        #pragma unroll
        for (int ks=0; ks<2; ++ks){
            short8 aN = *(const short8*)&sN[buf][(wt*16 + l15)*PAD + ks*32 + quad*8];
            short8 bU = *(const short8*)&sUt[(dq + l15)*PAD + ks*32 + quad*8];
            accO = __builtin_amdgcn_mfma_f32_16x16x32_bf16(aN, bU, accO, 0,0,0);
        }
        const float rl = sr[buf][63];
        floatx4 accS;
        #pragma unroll
        for (int r=0;r<4;++r) accS[r] = rl*Sreg[r];
        #pragma unroll
        for (int ks=0; ks<2; ++ks){
            short8 aU = *(const short8*)&sUt[(dq + l15)*PAD + ks*32 + quad*8];
            short8 bK = *(const short8*)&sKt2[(wt*16 + l15)*PAD + ks*32 + quad*8];
            accS = __builtin_amdgcn_mfma_f32_16x16x32_bf16(aU, bK, accS, 0,0,0);
        }
        Sreg = accS;

        #pragma unroll
        for (int r=0;r<4;++r)
            out[(size_t)(c*64 + t0 + r)*8192 + outBase + dq + l15] = accO[r];
        #pragma unroll
        for (int r=0;r<4;++r)
            sS0b[(d2base + r)*PAD + wt*16 + l15] = f2bf(Sreg[r]);

        if (c < 15){
            const int t = tid>>3, i8 = tid&7;
            *(float4*)&sK[t*PAD + i8*8]         = kst;
            *(float4*)&sQ[t*PAD + i8*8]         = qst;
            *(float4*)&sWt[t*PAD + i8*8]        = wst;
            *(float4*)&sN[buf^1][t*PAD + i8*8]  = nst;
            if (tid < 64) sr[buf^1][tid] = rst;
            #pragma unroll
            for (int r=0;r<4;++r) vCur[r] = vNext[r];
        }
        __syncthreads();   // C: end of chunk
    }

    // final state
    #pragma unroll
    for (int r=0;r<4;++r)
        out[(size_t)8388608 + (size_t)bh*4096 + (half*32 + d2base + r)*64 + wt*16 + l15] = Sreg[r];
}

extern "C" void kernel_launch(void* const* d_in, const int* in_sizes, int n_in,
                              void* d_out, int out_size, void* d_ws, size_t ws_size,
                              hipStream_t stream){
    const float* x  = (const float*)d_in[0];
    const float* S0 = (const float*)d_in[1];
    const float* Wq = (const float*)d_in[2];
    const float* Wk = (const float*)d_in[3];
    const float* Wv = (const float*)d_in[4];
    const float* Wa = (const float*)d_in[5];
    const float* ba = (const float*)d_in[6];
    const float* Wb = (const float*)d_in[7];
    const float* bb = (const float*)d_in[8];
    float* out = (float*)d_out;

    char* ws = (char*)d_ws;
    unsigned short* Abf = (unsigned short*)ws;                    // 16,777,216
    unsigned short* Bbf = (unsigned short*)(ws + 16777216);       // 10,485,760
    unsigned char*  KQV = (unsigned char*) (ws + 27262976);       // 67,108,864 (128*1024*512)
    float*          G   = (float*)         (ws + 94371840);       //  1,048,576
    unsigned short* Wtg = (unsigned short*)(ws + 95420416);       // 16,777,216 (2048*4096 bf16)
    unsigned short* Ng  = (unsigned short*)(ws + 112197632);      // 16,777,216
    float*          rg  = (float*)         (ws + 128974848);      //    524,288  -> end 129,499,136

    cvt_all<<<3328, 256, 0, stream>>>(x, Wq, Wk, Wv, Wa, Wb, Abf, Bbf);

    dim3 gg(N_COLS/256, M_ROWS/256);   // 20 x 32 = 640 blocks, 512 threads
    gemm_bt<<<gg, 512, 0, stream>>>(Abf, Bbf, KQV, G, ba, bb);

    phasea<<<2048, 256, 0, stream>>>(KQV, G, Wtg, Ng, rg);

    chunk_scan<<<256, 512, 0, stream>>>(KQV, Wtg, Ng, rg, S0, out);
}